// Round 1
// baseline (1999.559 us; speedup 1.0000x reference)
//
#include <hip/hip_runtime.h>
#include <math.h>

#define BATCH 2048
#define DIN 768
#define DICT 24576
#define KM 32
#define KA 512
#define NPT 48            // DICT / 512 elements per thread
#define L1_COEFF 0.001f
#define AUX_PENALTY 0.03125f
#define UZERO 0x80000000u
#define UMNEG1 0x407FFFFFu   // umap(-1.0f)

// ---------------- ws layout (float slots) ----------------
constexpr size_t WS_XENC   = 0;                              // BATCH*DIN
constexpr size_t WS_YN     = WS_XENC + (size_t)BATCH*DIN;    // BATCH*DIN
constexpr size_t WS_YMEAN  = WS_YN + (size_t)BATCH*DIN;      // BATCH
constexpr size_t WS_YSTD   = WS_YMEAN + BATCH;               // BATCH
constexpr size_t WS_RES    = WS_YSTD + BATCH;                // BATCH*DIN
constexpr size_t WS_NSEL   = WS_RES + (size_t)BATCH*DIN;     // BATCH (int)
constexpr size_t WS_SEL    = WS_NSEL + BATCH;                // BATCH*KM (int)
constexpr size_t WS_COLACT = WS_SEL + (size_t)BATCH*KM;      // DICT (int, memset 0)
constexpr size_t WS_ACC    = WS_COLACT + DICT;               // 8 (memset 0)
constexpr size_t WS_DB     = WS_ACC + 8;                     // DICT/32 words
// ACC: 0 l2_sum, 1 l1_sum, 2 l0_sum, 3 aux_sq, 4 numdead, 5 anydead(int)

__device__ __forceinline__ unsigned umap(float f){
    unsigned u = __float_as_uint(f);
    return (u & 0x80000000u) ? ~u : (u | 0x80000000u);
}
__device__ __forceinline__ float posval(unsigned u){ return __uint_as_float(u & 0x7fffffffu); }

// block-wide int sum for 512-thread blocks (8 waves). One barrier per call;
// callers must alternate `par` between consecutive calls.
__device__ __forceinline__ int blk_count512(int c, int* s16, int par){
    #pragma unroll
    for (int off=32; off; off>>=1) c += __shfl_down(c, off);
    if ((threadIdx.x & 63) == 0) s16[par*8 + (threadIdx.x >> 6)] = c;
    __syncthreads();
    int tot = 0;
    #pragma unroll
    for (int w=0; w<8; w++) tot += s16[par*8+w];
    return tot;
}
__device__ __forceinline__ float blk_sum512(float v, float* s16, int par){
    #pragma unroll
    for (int off=32; off; off>>=1) v += __shfl_down(v, off);
    if ((threadIdx.x & 63) == 0) s16[par*8 + (threadIdx.x >> 6)] = v;
    __syncthreads();
    float t = 0.f;
    #pragma unroll
    for (int w=0; w<8; w++) t += s16[par*8+w];
    return t;
}
__device__ __forceinline__ float blk_sum256(float v, float* s8, int par){
    #pragma unroll
    for (int off=32; off; off>>=1) v += __shfl_down(v, off);
    if ((threadIdx.x & 63) == 0) s8[par*4 + (threadIdx.x >> 6)] = v;
    __syncthreads();
    float t = 0.f;
    #pragma unroll
    for (int w=0; w<4; w++) t += s8[par*4+w];
    return t;
}

// ---------------- kernel A: per-row unit-norm (torch-style, ddof=1) ----------
__global__ __launch_bounds__(256) void normalize_k(const float* __restrict__ x,
        const float* __restrict__ y, const float* __restrict__ bdec,
        float* __restrict__ ws){
    __shared__ float s8[8];
    int b = blockIdx.x; bool isy = b >= BATCH; int row = isy ? b - BATCH : b;
    const float* src = (isy ? y : x) + (size_t)row*DIN;
    int tid = threadIdx.x;
    float v0 = src[tid], v1 = src[tid+256], v2 = src[tid+512];
    float s = blk_sum256(v0+v1+v2, s8, 0);
    float mean = s * (1.f/(float)DIN);
    float d0 = v0-mean, d1 = v1-mean, d2 = v2-mean;
    float vs = blk_sum256(d0*d0+d1*d1+d2*d2, s8, 1);
    float sd = sqrtf(vs / (float)(DIN-1));
    float inv = 1.f / (sd + 1e-5f);
    if (isy){
        float* yn = ws + WS_YN + (size_t)row*DIN;
        yn[tid] = d0*inv; yn[tid+256] = d1*inv; yn[tid+512] = d2*inv;
        if (tid==0){ ws[WS_YMEAN+row] = mean; ws[WS_YSTD+row] = sd; }
    } else {
        float* xe = ws + WS_XENC + (size_t)row*DIN;
        xe[tid]     = d0*inv - bdec[tid];
        xe[tid+256] = d1*inv - bdec[tid+256];
        xe[tid+512] = d2*inv - bdec[tid+512];
    }
}

// ---------------- kernel B: fp32 GEMM + relu, acts -> d_out acts region ------
__global__ __launch_bounds__(256) void gemm_relu(const float* __restrict__ A,
        const float* __restrict__ B, float* __restrict__ C){
    __shared__ float As[16][128];
    __shared__ float Bs[16][128];
    const int bn = blockIdx.x, bm = blockIdx.y;
    const int tid = threadIdx.x;
    const int tx = tid & 15, ty = tid >> 4;
    const int m0 = bm*128, n0 = bn*128;
    float acc[8][8];
    #pragma unroll
    for (int i=0;i<8;i++)
        #pragma unroll
        for (int j=0;j<8;j++) acc[i][j] = 0.f;
    for (int kt=0; kt<DIN; kt+=16){
        #pragma unroll
        for (int l=0;l<2;l++){
            int c = tid + l*256;
            int am = c >> 2, ak = (c & 3) << 2;
            float4 av = *(const float4*)&A[(size_t)(m0+am)*DIN + kt + ak];
            As[ak+0][am]=av.x; As[ak+1][am]=av.y; As[ak+2][am]=av.z; As[ak+3][am]=av.w;
            int bk = c >> 5, bn4 = (c & 31) << 2;
            *(float4*)&Bs[bk][bn4] = *(const float4*)&B[(size_t)(kt+bk)*DICT + n0 + bn4];
        }
        __syncthreads();
        #pragma unroll
        for (int kk=0; kk<16; kk++){
            float ar[8], br[8];
            *(float4*)&ar[0] = *(const float4*)&As[kk][ty*8];
            *(float4*)&ar[4] = *(const float4*)&As[kk][ty*8+4];
            *(float4*)&br[0] = *(const float4*)&Bs[kk][tx*8];
            *(float4*)&br[4] = *(const float4*)&Bs[kk][tx*8+4];
            #pragma unroll
            for (int i=0;i<8;i++)
                #pragma unroll
                for (int j=0;j<8;j++) acc[i][j] = fmaf(ar[i], br[j], acc[i][j]);
        }
        __syncthreads();
    }
    #pragma unroll
    for (int i=0;i<8;i++){
        size_t off = (size_t)(m0 + ty*8 + i)*DICT + n0 + tx*8;
        float4 o0, o1;
        o0.x=fmaxf(acc[i][0],0.f); o0.y=fmaxf(acc[i][1],0.f);
        o0.z=fmaxf(acc[i][2],0.f); o0.w=fmaxf(acc[i][3],0.f);
        o1.x=fmaxf(acc[i][4],0.f); o1.y=fmaxf(acc[i][5],0.f);
        o1.z=fmaxf(acc[i][6],0.f); o1.w=fmaxf(acc[i][7],0.f);
        *(float4*)&C[off]   = o0;
        *(float4*)&C[off+4] = o1;
    }
}

// ---------------- kernel C1: per-row exact top-32 + main epilogue ------------
__global__ __launch_bounds__(512) void topk_main(const float* __restrict__ acts,
        const float* __restrict__ Wdec, const float* __restrict__ bdec,
        float* __restrict__ ws, float* __restrict__ ypred_out){
    const int row = blockIdx.x, tid = threadIdx.x;
    const int lane = tid & 63, wid = tid >> 6;
    __shared__ int   s_i16[16];
    __shared__ float s_f16[16];
    __shared__ int   s_li[KM];
    __shared__ float s_lv[KM];
    __shared__ int   s_n;
    const float* arow = acts + (size_t)row * DICT;
    unsigned u[NPT];
    #pragma unroll
    for (int i=0;i<NPT;i++) u[i] = umap(arow[tid + 512*i]);

    int par = 0;
    unsigned prefix = 0;
    for (int bit=31; bit>=0; bit--){
        unsigned cand = prefix | (1u<<bit);
        int c = 0;
        #pragma unroll
        for (int i=0;i<NPT;i++) c += (u[i] >= cand) ? 1 : 0;
        int tot = blk_count512(c, s_i16, par); par ^= 1;
        if (tot >= KM) prefix = cand;
    }
    int cgt=0, ceq=0;
    #pragma unroll
    for (int i=0;i<NPT;i++){ cgt += (u[i] > prefix); ceq += (u[i] == prefix); }
    int cgt_t = blk_count512(cgt, s_i16, par); par ^= 1;
    int ceq_t = blk_count512(ceq, s_i16, par); par ^= 1;
    int m = KM - cgt_t;
    if (tid==0) s_n = 0;
    __syncthreads();
    unsigned thr = prefix > UZERO ? prefix : UZERO;
    #pragma unroll
    for (int i=0;i<NPT;i++){
        if (u[i] > thr){
            int p = atomicAdd(&s_n, 1);
            s_li[p] = tid + 512*i; s_lv[p] = posval(u[i]);
        }
    }
    __syncthreads();
    if (prefix > UZERO && m > 0){
        if (ceq_t == m){
            #pragma unroll
            for (int i=0;i<NPT;i++){
                if (u[i] == prefix){
                    int p = atomicAdd(&s_n, 1);
                    s_li[p] = tid + 512*i; s_lv[p] = posval(prefix);
                }
            }
        } else {
            // rare: exact duplicates at the cutoff -> lowest-index-first quota
            int seen = 0;
            for (int i=0;i<NPT;i++){
                int j = tid + 512*i;
                bool match = (umap(arow[j]) == prefix);
                unsigned long long bal = __ballot(match ? 1 : 0);
                if (lane==0) s_i16[par*8+wid] = __popcll(bal);
                __syncthreads();
                int before=0, tot=0;
                for (int w=0;w<8;w++){ int v = s_i16[par*8+w]; if (w<wid) before += v; tot += v; }
                par ^= 1;
                int rank = seen + before + __popcll(bal & ((1ull<<lane)-1ull));
                if (match && rank < m){
                    int p = atomicAdd(&s_n, 1);
                    s_li[p] = j; s_lv[p] = posval(prefix);
                }
                seen += tot;
            }
        }
    }
    __syncthreads();
    int n = s_n;
    if (tid < n){
        ((int*)ws)[WS_COLACT + s_li[tid]] = 1;
        ((int*)ws)[WS_SEL + (size_t)row*KM + tid] = s_li[tid];
    }
    if (tid == 0){
        ((int*)ws)[WS_NSEL + row] = n;
        float l1 = 0.f;
        for (int l=0;l<n;l++) l1 += s_lv[l];
        atomicAdd(&ws[WS_ACC+1], l1);
        atomicAdd(&ws[WS_ACC+2], (float)n);
    }
    __syncthreads();
    float ym = ws[WS_YMEAN+row], ys = ws[WS_YSTD+row];
    float l2loc = 0.f;
    for (int c = tid; c < DIN; c += 512){
        float acc = bdec[c];
        for (int l=0;l<n;l++) acc = fmaf(s_lv[l], Wdec[(size_t)s_li[l]*DIN + c], acc);
        float ynv = ws[WS_YN + (size_t)row*DIN + c];
        float d = acc - ynv;
        l2loc += d*d;
        ws[WS_RES + (size_t)row*DIN + c] = ynv - acc;
        ypred_out[(size_t)row*DIN + c] = fmaf(acc, ys, ym);
    }
    float l2t = blk_sum512(l2loc, s_f16, 0);
    if (tid==0) atomicAdd(&ws[WS_ACC+0], l2t);
}

// ---------------- kernel D: dead-feature bookkeeping -------------------------
__global__ __launch_bounds__(256) void dead_update(const float* __restrict__ nb,
        float* __restrict__ ws){
    int j = blockIdx.x*256 + threadIdx.x;
    int lane = threadIdx.x & 63;
    int act = ((const int*)ws)[WS_COLACT + j];
    float nbn = act ? 0.f : nb[j] + 1.f;
    bool dead = nbn >= 100.0f;
    unsigned long long bal = __ballot(dead ? 1 : 0);
    if (lane == 0){
        unsigned* db = (unsigned*)(ws + WS_DB);
        int w = j >> 5;
        db[w]   = (unsigned)bal;
        db[w+1] = (unsigned)(bal >> 32);
        if (bal) atomicOr(((int*)ws) + WS_ACC + 5, 1);
    }
    int c = (nbn > 100.0f) ? 1 : 0;
    #pragma unroll
    for (int off=32; off; off>>=1) c += __shfl_down(c, off);
    if (lane == 0 && c) atomicAdd(&ws[WS_ACC+4], (float)c);
}

// ---------------- kernel E: aux top-512, sparse rewrite, aux loss ------------
__global__ __launch_bounds__(512) void aux_and_write(float* __restrict__ acts,
        const float* __restrict__ Wdec, float* __restrict__ ws){
    const int row = blockIdx.x, tid = threadIdx.x;
    const int lane = tid & 63, wid = tid >> 6;
    __shared__ int      s_i16[16];
    __shared__ float    s_f16[16];
    __shared__ unsigned s_db[DICT/32];
    __shared__ unsigned s_keep[DICT/32];
    __shared__ int      s_li[KA];
    __shared__ float    s_lv[KA];
    __shared__ int      s_n;
    __shared__ float    s_red[DIN];
    float* arow = acts + (size_t)row * DICT;

    for (int i=tid; i<DICT/32; i+=512){
        s_db[i]   = ((const unsigned*)(ws + WS_DB))[i];
        s_keep[i] = 0u;
    }
    if (tid==0) s_n = 0;
    __syncthreads();

    unsigned u[NPT];
    unsigned long long dm = 0ull;
    #pragma unroll
    for (int i=0;i<NPT;i++){
        int j = tid + 512*i;
        u[i] = umap(arow[j]);
        if ((s_db[j>>5] >> (j&31)) & 1u) dm |= (1ull << i);
    }

    int par = 0;
    unsigned prefix = 0;
    for (int bit=31; bit>=0; bit--){
        unsigned cand = prefix | (1u<<bit);
        int c = 0;
        #pragma unroll
        for (int i=0;i<NPT;i++){
            unsigned um = ((dm>>i)&1ull) ? u[i] : UMNEG1;
            c += (um >= cand) ? 1 : 0;
        }
        int tot = blk_count512(c, s_i16, par); par ^= 1;
        if (tot >= KA) prefix = cand;
    }
    int cgt=0, ceq=0;
    #pragma unroll
    for (int i=0;i<NPT;i++){
        unsigned um = ((dm>>i)&1ull) ? u[i] : UMNEG1;
        cgt += (um > prefix); ceq += (um == prefix);
    }
    int cgt_t = blk_count512(cgt, s_i16, par); par ^= 1;
    int ceq_t = blk_count512(ceq, s_i16, par); par ^= 1;
    int m = KA - cgt_t;
    unsigned thr = prefix > UZERO ? prefix : UZERO;
    #pragma unroll
    for (int i=0;i<NPT;i++){
        unsigned um = ((dm>>i)&1ull) ? u[i] : UMNEG1;
        if (um > thr){
            int p = atomicAdd(&s_n, 1);
            s_li[p] = tid + 512*i; s_lv[p] = posval(u[i]);
        }
    }
    __syncthreads();
    if (prefix > UZERO && m > 0){
        if (ceq_t == m){
            #pragma unroll
            for (int i=0;i<NPT;i++){
                unsigned um = ((dm>>i)&1ull) ? u[i] : UMNEG1;
                if (um == prefix){
                    int p = atomicAdd(&s_n, 1);
                    s_li[p] = tid + 512*i; s_lv[p] = posval(prefix);
                }
            }
        } else {
            int seen = 0;
            for (int i=0;i<NPT;i++){
                int j = tid + 512*i;
                unsigned uv = umap(arow[j]);
                unsigned um = ((s_db[j>>5]>>(j&31))&1u) ? uv : UMNEG1;
                bool match = (um == prefix);
                unsigned long long bal = __ballot(match ? 1 : 0);
                if (lane==0) s_i16[par*8+wid] = __popcll(bal);
                __syncthreads();
                int before=0, tot=0;
                for (int w=0;w<8;w++){ int v=s_i16[par*8+w]; if (w<wid) before+=v; tot+=v; }
                par ^= 1;
                int rank = seen + before + __popcll(bal & ((1ull<<lane)-1ull));
                if (match && rank < m){
                    int p = atomicAdd(&s_n, 1);
                    s_li[p] = j; s_lv[p] = posval(uv);
                }
                seen += tot;
            }
        }
    }
    __syncthreads();
    int n = s_n;

    // main selection -> keep bitmap (from C1's persisted list), rewrite row
    int nm = ((const int*)ws)[WS_NSEL + row];
    if (tid < nm){
        int j = ((const int*)ws)[WS_SEL + (size_t)row*KM + tid];
        atomicOr(&s_keep[j>>5], 1u << (j&31));
    }
    __syncthreads();
    #pragma unroll
    for (int i=0;i<NPT;i++){
        int j = tid + 512*i;
        bool keep = (s_keep[j>>5] >> (j&31)) & 1u;
        arow[j] = keep ? posval(u[i]) : 0.f;
    }

    // aux epilogue: y_aux = sum vals * W_dec rows; aux_sq += ||y_aux - residual||^2
    float4 a = make_float4(0.f,0.f,0.f,0.f);
    int g = tid / 192;
    int cq = (tid % 192) * 4;
    if (g < 2){
        for (int l=g; l<n; l+=2){
            float v = s_lv[l];
            const float4 w = *(const float4*)&Wdec[(size_t)s_li[l]*DIN + cq];
            a.x = fmaf(v, w.x, a.x); a.y = fmaf(v, w.y, a.y);
            a.z = fmaf(v, w.z, a.z); a.w = fmaf(v, w.w, a.w);
        }
    }
    __syncthreads();
    if (g == 1) *(float4*)&s_red[cq] = a;
    __syncthreads();
    float ss = 0.f;
    if (g == 0){
        float4 b = *(const float4*)&s_red[cq];
        const float4 r = *(const float4*)&ws[WS_RES + (size_t)row*DIN + cq];
        float dx = a.x + b.x - r.x, dy = a.y + b.y - r.y;
        float dz = a.z + b.z - r.z, dw = a.w + b.w - r.w;
        ss = dx*dx + dy*dy + dz*dz + dw*dw;
    }
    float tot = blk_sum512(ss, s_f16, 0);
    if (tid==0) atomicAdd(&ws[WS_ACC+3], tot);
}

// ---------------- kernel F: scalars ------------------------------------------
__global__ void finalize_k(const float* __restrict__ ws, float* __restrict__ out){
    if (threadIdx.x == 0){
        float l2   = ws[WS_ACC+0] / (float)((size_t)BATCH*DIN);
        float l1n  = ws[WS_ACC+1] / (float)BATCH;
        float l1l  = L1_COEFF * l1n;
        float l0   = ws[WS_ACC+2] / (float)BATCH;
        float auxm = AUX_PENALTY * (ws[WS_ACC+3] / (float)((size_t)BATCH*DIN));
        int any    = ((const int*)ws)[WS_ACC+5];
        float auxl = any ? auxm : 0.f;
        out[0] = l2 + l1l + auxl;
        out[1] = l2;
        out[2] = l1l;
        out[3] = l0;
        out[4] = l1n;
        out[5] = auxl;
        out[6] = ws[WS_ACC+4];
    }
}

extern "C" void kernel_launch(void* const* d_in, const int* in_sizes, int n_in,
                              void* d_out, int out_size, void* d_ws, size_t ws_size,
                              hipStream_t stream){
    const float* x_in = (const float*)d_in[0];
    const float* y_t  = (const float*)d_in[1];
    const float* nb   = (const float*)d_in[2];
    const float* Wenc = (const float*)d_in[3];
    const float* Wdec = (const float*)d_in[4];
    const float* bdec = (const float*)d_in[5];
    float* out  = (float*)d_out;
    float* ws   = (float*)d_ws;
    float* acts = out + (size_t)BATCH*DIN;                       // acts_sparse region
    float* scal = out + (size_t)BATCH*DIN + (size_t)BATCH*DICT;  // 7 scalars

    hipMemsetAsync(ws + WS_COLACT, 0, (DICT + 8) * sizeof(float), stream);
    normalize_k<<<2*BATCH, 256, 0, stream>>>(x_in, y_t, bdec, ws);
    gemm_relu<<<dim3(DICT/128, BATCH/128), 256, 0, stream>>>(ws + WS_XENC, Wenc, acts);
    topk_main<<<BATCH, 512, 0, stream>>>(acts, Wdec, bdec, ws, out);
    dead_update<<<DICT/256, 256, 0, stream>>>(nb, ws);
    aux_and_write<<<BATCH, 512, 0, stream>>>(acts, Wdec, ws);
    finalize_k<<<1, 64, 0, stream>>>(ws, scal);
}

// Round 2
// 1933.438 us; speedup vs baseline: 1.0342x; 1.0342x over previous
//
#include <hip/hip_runtime.h>
#include <math.h>

#define BATCH 2048
#define DIN 768
#define DICT 24576
#define KM 32
#define KA 512
#define NPT 48            // DICT / 512 elements per thread
#define L1_COEFF 0.001f
#define AUX_PENALTY 0.03125f
#define UZERO 0x80000000u
#define UMNEG1 0x407FFFFFu   // umap(-1.0f)

// ---------------- ws layout (float slots) ----------------
constexpr size_t WS_XENC   = 0;                              // BATCH*DIN
constexpr size_t WS_YN     = WS_XENC + (size_t)BATCH*DIN;    // BATCH*DIN
constexpr size_t WS_YMEAN  = WS_YN + (size_t)BATCH*DIN;      // BATCH
constexpr size_t WS_YSTD   = WS_YMEAN + BATCH;               // BATCH
constexpr size_t WS_RES    = WS_YSTD + BATCH;                // BATCH*DIN
constexpr size_t WS_NSEL   = WS_RES + (size_t)BATCH*DIN;     // BATCH (int)
constexpr size_t WS_SEL    = WS_NSEL + BATCH;                // BATCH*KM (int)
constexpr size_t WS_COLACT = WS_SEL + (size_t)BATCH*KM;      // DICT (int, memset 0)
constexpr size_t WS_ACC    = WS_COLACT + DICT;               // 8 (memset 0)
constexpr size_t WS_DB     = WS_ACC + 8;                     // DICT/32 words
// ACC: 0 l2_sum, 1 l1_sum, 2 l0_sum, 3 aux_sq, 4 numdead, 5 anydead(int)

__device__ __forceinline__ unsigned umap(float f){
    unsigned u = __float_as_uint(f);
    return (u & 0x80000000u) ? ~u : (u | 0x80000000u);
}
__device__ __forceinline__ float posval(unsigned u){ return __uint_as_float(u & 0x7fffffffu); }

// block-wide int sum for 512-thread blocks (8 waves). One barrier per call;
// callers must alternate `par` between consecutive calls.
__device__ __forceinline__ int blk_count512(int c, int* s16, int par){
    #pragma unroll
    for (int off=32; off; off>>=1) c += __shfl_down(c, off);
    if ((threadIdx.x & 63) == 0) s16[par*8 + (threadIdx.x >> 6)] = c;
    __syncthreads();
    int tot = 0;
    #pragma unroll
    for (int w=0; w<8; w++) tot += s16[par*8+w];
    return tot;
}
__device__ __forceinline__ float blk_sum512(float v, float* s16, int par){
    #pragma unroll
    for (int off=32; off; off>>=1) v += __shfl_down(v, off);
    if ((threadIdx.x & 63) == 0) s16[par*8 + (threadIdx.x >> 6)] = v;
    __syncthreads();
    float t = 0.f;
    #pragma unroll
    for (int w=0; w<8; w++) t += s16[par*8+w];
    return t;
}
__device__ __forceinline__ float blk_sum256(float v, float* s8, int par){
    #pragma unroll
    for (int off=32; off; off>>=1) v += __shfl_down(v, off);
    if ((threadIdx.x & 63) == 0) s8[par*4 + (threadIdx.x >> 6)] = v;
    __syncthreads();
    float t = 0.f;
    #pragma unroll
    for (int w=0; w<4; w++) t += s8[par*4+w];
    return t;
}

// ---------------- kernel A: per-row unit-norm (torch-style, ddof=1) ----------
__global__ __launch_bounds__(256) void normalize_k(const float* __restrict__ x,
        const float* __restrict__ y, const float* __restrict__ bdec,
        float* __restrict__ ws){
    __shared__ float s8[8];
    int b = blockIdx.x; bool isy = b >= BATCH; int row = isy ? b - BATCH : b;
    const float* src = (isy ? y : x) + (size_t)row*DIN;
    int tid = threadIdx.x;
    float v0 = src[tid], v1 = src[tid+256], v2 = src[tid+512];
    float s = blk_sum256(v0+v1+v2, s8, 0);
    float mean = s * (1.f/(float)DIN);
    float d0 = v0-mean, d1 = v1-mean, d2 = v2-mean;
    float vs = blk_sum256(d0*d0+d1*d1+d2*d2, s8, 1);
    float sd = sqrtf(vs / (float)(DIN-1));
    float inv = 1.f / (sd + 1e-5f);
    if (isy){
        float* yn = ws + WS_YN + (size_t)row*DIN;
        yn[tid] = d0*inv; yn[tid+256] = d1*inv; yn[tid+512] = d2*inv;
        if (tid==0){ ws[WS_YMEAN+row] = mean; ws[WS_YSTD+row] = sd; }
    } else {
        float* xe = ws + WS_XENC + (size_t)row*DIN;
        xe[tid]     = d0*inv - bdec[tid];
        xe[tid+256] = d1*inv - bdec[tid+256];
        xe[tid+512] = d2*inv - bdec[tid+512];
    }
}

// ---------------- kernel B: fp32 GEMM + relu, acts -> d_out acts region ------
// 128x128 tile, 256 threads, 8x8 micro-tile as 4+4 split so all LDS fragment
// reads are lane-consecutive float4 (<=2-way bank aliasing = free).
// As padded [16][132]: transpose-store becomes 2-way instead of 4-way.
__global__ __launch_bounds__(256) void gemm_relu(const float* __restrict__ A,
        const float* __restrict__ B, float* __restrict__ C){
    __shared__ float As[16][132];
    __shared__ float Bs[16][128];
    const int bn = blockIdx.x, bm = blockIdx.y;
    const int tid = threadIdx.x;
    const int tx = tid & 15, ty = tid >> 4;
    const int m0 = bm*128, n0 = bn*128;
    float acc[8][8];
    #pragma unroll
    for (int i=0;i<8;i++)
        #pragma unroll
        for (int j=0;j<8;j++) acc[i][j] = 0.f;
    for (int kt=0; kt<DIN; kt+=16){
        #pragma unroll
        for (int l=0;l<2;l++){
            int c = tid + l*256;
            int am = c >> 2, ak = (c & 3) << 2;
            float4 av = *(const float4*)&A[(size_t)(m0+am)*DIN + kt + ak];
            As[ak+0][am]=av.x; As[ak+1][am]=av.y; As[ak+2][am]=av.z; As[ak+3][am]=av.w;
            int bk = c >> 5, bn4 = (c & 31) << 2;
            *(float4*)&Bs[bk][bn4] = *(const float4*)&B[(size_t)(kt+bk)*DICT + n0 + bn4];
        }
        __syncthreads();
        #pragma unroll
        for (int kk=0; kk<16; kk++){
            float ar[8], br[8];
            *(float4*)&ar[0] = *(const float4*)&As[kk][ty*4];
            *(float4*)&ar[4] = *(const float4*)&As[kk][64 + ty*4];
            *(float4*)&br[0] = *(const float4*)&Bs[kk][tx*4];
            *(float4*)&br[4] = *(const float4*)&Bs[kk][64 + tx*4];
            #pragma unroll
            for (int i=0;i<8;i++)
                #pragma unroll
                for (int j=0;j<8;j++) acc[i][j] = fmaf(ar[i], br[j], acc[i][j]);
        }
        __syncthreads();
    }
    #pragma unroll
    for (int i=0;i<8;i++){
        int mrow = m0 + ((i<4) ? (ty*4 + i) : (64 + ty*4 + i - 4));
        size_t off = (size_t)mrow*DICT + n0;
        float4 o0, o1;
        o0.x=fmaxf(acc[i][0],0.f); o0.y=fmaxf(acc[i][1],0.f);
        o0.z=fmaxf(acc[i][2],0.f); o0.w=fmaxf(acc[i][3],0.f);
        o1.x=fmaxf(acc[i][4],0.f); o1.y=fmaxf(acc[i][5],0.f);
        o1.z=fmaxf(acc[i][6],0.f); o1.w=fmaxf(acc[i][7],0.f);
        *(float4*)&C[off + tx*4]      = o0;
        *(float4*)&C[off + 64 + tx*4] = o1;
    }
}

// ---------------- kernel C1: per-row exact top-32 + main epilogue ------------
__global__ __launch_bounds__(512) void topk_main(const float* __restrict__ acts,
        const float* __restrict__ Wdec, const float* __restrict__ bdec,
        float* __restrict__ ws, float* __restrict__ ypred_out){
    const int row = blockIdx.x, tid = threadIdx.x;
    const int lane = tid & 63, wid = tid >> 6;
    __shared__ int   s_i16[16];
    __shared__ float s_f16[16];
    __shared__ int   s_li[KM];
    __shared__ float s_lv[KM];
    __shared__ int   s_n;
    const float* arow = acts + (size_t)row * DICT;
    unsigned u[NPT];
    #pragma unroll
    for (int i=0;i<NPT;i++) u[i] = umap(arow[tid + 512*i]);

    int par = 0;
    unsigned prefix = 0;
    for (int bit=31; bit>=0; bit--){
        unsigned cand = prefix | (1u<<bit);
        int c = 0;
        #pragma unroll
        for (int i=0;i<NPT;i++) c += (u[i] >= cand) ? 1 : 0;
        int tot = blk_count512(c, s_i16, par); par ^= 1;
        if (tot >= KM) prefix = cand;
    }
    int cgt=0, ceq=0;
    #pragma unroll
    for (int i=0;i<NPT;i++){ cgt += (u[i] > prefix); ceq += (u[i] == prefix); }
    int cgt_t = blk_count512(cgt, s_i16, par); par ^= 1;
    int ceq_t = blk_count512(ceq, s_i16, par); par ^= 1;
    int m = KM - cgt_t;
    if (tid==0) s_n = 0;
    __syncthreads();
    unsigned thr = prefix > UZERO ? prefix : UZERO;
    #pragma unroll
    for (int i=0;i<NPT;i++){
        if (u[i] > thr){
            int p = atomicAdd(&s_n, 1);
            s_li[p] = tid + 512*i; s_lv[p] = posval(u[i]);
        }
    }
    __syncthreads();
    if (prefix > UZERO && m > 0){
        if (ceq_t == m){
            #pragma unroll
            for (int i=0;i<NPT;i++){
                if (u[i] == prefix){
                    int p = atomicAdd(&s_n, 1);
                    s_li[p] = tid + 512*i; s_lv[p] = posval(prefix);
                }
            }
        } else {
            // rare: exact duplicates at the cutoff -> lowest-index-first quota
            int seen = 0;
            for (int i=0;i<NPT;i++){
                int j = tid + 512*i;
                bool match = (umap(arow[j]) == prefix);
                unsigned long long bal = __ballot(match ? 1 : 0);
                if (lane==0) s_i16[par*8+wid] = __popcll(bal);
                __syncthreads();
                int before=0, tot=0;
                for (int w=0;w<8;w++){ int v = s_i16[par*8+w]; if (w<wid) before += v; tot += v; }
                par ^= 1;
                int rank = seen + before + __popcll(bal & ((1ull<<lane)-1ull));
                if (match && rank < m){
                    int p = atomicAdd(&s_n, 1);
                    s_li[p] = j; s_lv[p] = posval(prefix);
                }
                seen += tot;
            }
        }
    }
    __syncthreads();
    int n = s_n;
    if (tid < n){
        ((int*)ws)[WS_COLACT + s_li[tid]] = 1;
        ((int*)ws)[WS_SEL + (size_t)row*KM + tid] = s_li[tid];
    }
    if (tid == 0){
        ((int*)ws)[WS_NSEL + row] = n;
        float l1 = 0.f;
        for (int l=0;l<n;l++) l1 += s_lv[l];
        atomicAdd(&ws[WS_ACC+1], l1);
        atomicAdd(&ws[WS_ACC+2], (float)n);
    }
    __syncthreads();
    float ym = ws[WS_YMEAN+row], ys = ws[WS_YSTD+row];
    float l2loc = 0.f;
    for (int c = tid; c < DIN; c += 512){
        float acc = bdec[c];
        for (int l=0;l<n;l++) acc = fmaf(s_lv[l], Wdec[(size_t)s_li[l]*DIN + c], acc);
        float ynv = ws[WS_YN + (size_t)row*DIN + c];
        float d = acc - ynv;
        l2loc += d*d;
        ws[WS_RES + (size_t)row*DIN + c] = ynv - acc;
        ypred_out[(size_t)row*DIN + c] = fmaf(acc, ys, ym);
    }
    float l2t = blk_sum512(l2loc, s_f16, 0);
    if (tid==0) atomicAdd(&ws[WS_ACC+0], l2t);
}

// ---------------- kernel D: dead-feature bookkeeping -------------------------
__global__ __launch_bounds__(256) void dead_update(const float* __restrict__ nb,
        float* __restrict__ ws){
    int j = blockIdx.x*256 + threadIdx.x;
    int lane = threadIdx.x & 63;
    int act = ((const int*)ws)[WS_COLACT + j];
    float nbn = act ? 0.f : nb[j] + 1.f;
    bool dead = nbn >= 100.0f;
    unsigned long long bal = __ballot(dead ? 1 : 0);
    if (lane == 0){
        unsigned* db = (unsigned*)(ws + WS_DB);
        int w = j >> 5;
        db[w]   = (unsigned)bal;
        db[w+1] = (unsigned)(bal >> 32);
        if (bal) atomicOr(((int*)ws) + WS_ACC + 5, 1);
    }
    int c = (nbn > 100.0f) ? 1 : 0;
    #pragma unroll
    for (int off=32; off; off>>=1) c += __shfl_down(c, off);
    if (lane == 0 && c) atomicAdd(&ws[WS_ACC+4], (float)c);
}

// ---------------- kernel E: aux top-512, sparse rewrite, aux loss ------------
__global__ __launch_bounds__(512) void aux_and_write(float* __restrict__ acts,
        const float* __restrict__ Wdec, float* __restrict__ ws){
    const int row = blockIdx.x, tid = threadIdx.x;
    const int lane = tid & 63, wid = tid >> 6;
    __shared__ int      s_i16[16];
    __shared__ float    s_f16[16];
    __shared__ unsigned s_db[DICT/32];
    __shared__ unsigned s_keep[DICT/32];
    __shared__ int      s_li[KA];
    __shared__ float    s_lv[KA];
    __shared__ int      s_n;
    __shared__ float    s_red[DIN];
    float* arow = acts + (size_t)row * DICT;

    for (int i=tid; i<DICT/32; i+=512){
        s_db[i]   = ((const unsigned*)(ws + WS_DB))[i];
        s_keep[i] = 0u;
    }
    if (tid==0) s_n = 0;
    __syncthreads();

    unsigned u[NPT];
    unsigned long long dm = 0ull;
    #pragma unroll
    for (int i=0;i<NPT;i++){
        int j = tid + 512*i;
        u[i] = umap(arow[j]);
        if ((s_db[j>>5] >> (j&31)) & 1u) dm |= (1ull << i);
    }

    int par = 0;
    unsigned prefix = 0;
    for (int bit=31; bit>=0; bit--){
        unsigned cand = prefix | (1u<<bit);
        int c = 0;
        #pragma unroll
        for (int i=0;i<NPT;i++){
            unsigned um = ((dm>>i)&1ull) ? u[i] : UMNEG1;
            c += (um >= cand) ? 1 : 0;
        }
        int tot = blk_count512(c, s_i16, par); par ^= 1;
        if (tot >= KA) prefix = cand;
    }
    int cgt=0, ceq=0;
    #pragma unroll
    for (int i=0;i<NPT;i++){
        unsigned um = ((dm>>i)&1ull) ? u[i] : UMNEG1;
        cgt += (um > prefix); ceq += (um == prefix);
    }
    int cgt_t = blk_count512(cgt, s_i16, par); par ^= 1;
    int ceq_t = blk_count512(ceq, s_i16, par); par ^= 1;
    int m = KA - cgt_t;
    unsigned thr = prefix > UZERO ? prefix : UZERO;
    #pragma unroll
    for (int i=0;i<NPT;i++){
        unsigned um = ((dm>>i)&1ull) ? u[i] : UMNEG1;
        if (um > thr){
            int p = atomicAdd(&s_n, 1);
            s_li[p] = tid + 512*i; s_lv[p] = posval(u[i]);
        }
    }
    __syncthreads();
    if (prefix > UZERO && m > 0){
        if (ceq_t == m){
            #pragma unroll
            for (int i=0;i<NPT;i++){
                unsigned um = ((dm>>i)&1ull) ? u[i] : UMNEG1;
                if (um == prefix){
                    int p = atomicAdd(&s_n, 1);
                    s_li[p] = tid + 512*i; s_lv[p] = posval(prefix);
                }
            }
        } else {
            int seen = 0;
            for (int i=0;i<NPT;i++){
                int j = tid + 512*i;
                unsigned uv = umap(arow[j]);
                unsigned um = ((s_db[j>>5]>>(j&31))&1u) ? uv : UMNEG1;
                bool match = (um == prefix);
                unsigned long long bal = __ballot(match ? 1 : 0);
                if (lane==0) s_i16[par*8+wid] = __popcll(bal);
                __syncthreads();
                int before=0, tot=0;
                for (int w=0;w<8;w++){ int v=s_i16[par*8+w]; if (w<wid) before+=v; tot+=v; }
                par ^= 1;
                int rank = seen + before + __popcll(bal & ((1ull<<lane)-1ull));
                if (match && rank < m){
                    int p = atomicAdd(&s_n, 1);
                    s_li[p] = j; s_lv[p] = posval(uv);
                }
                seen += tot;
            }
        }
    }
    __syncthreads();
    int n = s_n;

    // main selection -> keep bitmap (from C1's persisted list), rewrite row
    int nm = ((const int*)ws)[WS_NSEL + row];
    if (tid < nm){
        int j = ((const int*)ws)[WS_SEL + (size_t)row*KM + tid];
        atomicOr(&s_keep[j>>5], 1u << (j&31));
    }
    __syncthreads();
    #pragma unroll
    for (int i=0;i<NPT;i++){
        int j = tid + 512*i;
        bool keep = (s_keep[j>>5] >> (j&31)) & 1u;
        arow[j] = keep ? posval(u[i]) : 0.f;
    }

    // aux epilogue: y_aux = sum vals * W_dec rows; aux_sq += ||y_aux - residual||^2
    float4 a = make_float4(0.f,0.f,0.f,0.f);
    int g = tid / 192;
    int cq = (tid % 192) * 4;
    if (g < 2){
        for (int l=g; l<n; l+=2){
            float v = s_lv[l];
            const float4 w = *(const float4*)&Wdec[(size_t)s_li[l]*DIN + cq];
            a.x = fmaf(v, w.x, a.x); a.y = fmaf(v, w.y, a.y);
            a.z = fmaf(v, w.z, a.z); a.w = fmaf(v, w.w, a.w);
        }
    }
    __syncthreads();
    if (g == 1) *(float4*)&s_red[cq] = a;
    __syncthreads();
    float ss = 0.f;
    if (g == 0){
        float4 b = *(const float4*)&s_red[cq];
        const float4 r = *(const float4*)&ws[WS_RES + (size_t)row*DIN + cq];
        float dx = a.x + b.x - r.x, dy = a.y + b.y - r.y;
        float dz = a.z + b.z - r.z, dw = a.w + b.w - r.w;
        ss = dx*dx + dy*dy + dz*dz + dw*dw;
    }
    float tot = blk_sum512(ss, s_f16, 0);
    if (tid==0) atomicAdd(&ws[WS_ACC+3], tot);
}

// ---------------- kernel F: scalars ------------------------------------------
__global__ void finalize_k(const float* __restrict__ ws, float* __restrict__ out){
    if (threadIdx.x == 0){
        float l2   = ws[WS_ACC+0] / (float)((size_t)BATCH*DIN);
        float l1n  = ws[WS_ACC+1] / (float)BATCH;
        float l1l  = L1_COEFF * l1n;
        float l0   = ws[WS_ACC+2] / (float)BATCH;
        float auxm = AUX_PENALTY * (ws[WS_ACC+3] / (float)((size_t)BATCH*DIN));
        int any    = ((const int*)ws)[WS_ACC+5];
        float auxl = any ? auxm : 0.f;
        out[0] = l2 + l1l + auxl;
        out[1] = l2;
        out[2] = l1l;
        out[3] = l0;
        out[4] = l1n;
        out[5] = auxl;
        out[6] = ws[WS_ACC+4];
    }
}

extern "C" void kernel_launch(void* const* d_in, const int* in_sizes, int n_in,
                              void* d_out, int out_size, void* d_ws, size_t ws_size,
                              hipStream_t stream){
    const float* x_in = (const float*)d_in[0];
    const float* y_t  = (const float*)d_in[1];
    const float* nb   = (const float*)d_in[2];
    const float* Wenc = (const float*)d_in[3];
    const float* Wdec = (const float*)d_in[4];
    const float* bdec = (const float*)d_in[5];
    float* out  = (float*)d_out;
    float* ws   = (float*)d_ws;
    float* acts = out + (size_t)BATCH*DIN;                       // acts_sparse region
    float* scal = out + (size_t)BATCH*DIN + (size_t)BATCH*DICT;  // 7 scalars

    hipMemsetAsync(ws + WS_COLACT, 0, (DICT + 8) * sizeof(float), stream);
    normalize_k<<<2*BATCH, 256, 0, stream>>>(x_in, y_t, bdec, ws);
    gemm_relu<<<dim3(DICT/128, BATCH/128), 256, 0, stream>>>(ws + WS_XENC, Wenc, acts);
    topk_main<<<BATCH, 512, 0, stream>>>(acts, Wdec, bdec, ws, out);
    dead_update<<<DICT/256, 256, 0, stream>>>(nb, ws);
    aux_and_write<<<BATCH, 512, 0, stream>>>(acts, Wdec, ws);
    finalize_k<<<1, 64, 0, stream>>>(ws, scal);
}

// Round 3
// 1384.894 us; speedup vs baseline: 1.4438x; 1.3961x over previous
//
#include <hip/hip_runtime.h>
#include <math.h>

#define BATCH 2048
#define DIN 768
#define DICT 24576
#define KM 32
#define KA 512
#define NPT 48            // DICT / 512 elements per thread
#define L1_COEFF 0.001f
#define AUX_PENALTY 0.03125f
#define UZERO 0x80000000u
#define UMNEG1 0x407FFFFFu   // umap(-1.0f)
#define CAND_MAX 128
#define CAND_DELTA 0.05f

typedef __attribute__((ext_vector_type(8))) short bf16x8;
typedef __attribute__((ext_vector_type(4))) float f32x4;

// ---------------- ws layout (float slots) ----------------
constexpr size_t WS_XENC   = 0;                              // BATCH*DIN f32 (refinement)
constexpr size_t WS_YN     = WS_XENC + (size_t)BATCH*DIN;    // BATCH*DIN
constexpr size_t WS_YMEAN  = WS_YN + (size_t)BATCH*DIN;      // BATCH
constexpr size_t WS_YSTD   = WS_YMEAN + BATCH;               // BATCH
constexpr size_t WS_RES    = WS_YSTD + BATCH;                // BATCH*DIN
constexpr size_t WS_NSEL   = WS_RES + (size_t)BATCH*DIN;     // BATCH (int)
constexpr size_t WS_SEL    = WS_NSEL + BATCH;                // BATCH*KM (int)
constexpr size_t WS_SELV   = WS_SEL + (size_t)BATCH*KM;      // BATCH*KM (float, exact vals)
constexpr size_t WS_COLACT = WS_SELV + (size_t)BATCH*KM;     // DICT (int, memset 0)
constexpr size_t WS_ACC    = WS_COLACT + DICT;               // 8 (memset 0)
constexpr size_t WS_DB     = WS_ACC + 8;                     // DICT/32 words
constexpr size_t WS_XEB    = WS_DB + DICT/32;                // BATCH*DIN bf16 -> /2 slots
constexpr size_t WS_WETF   = WS_XEB + (size_t)BATCH*DIN/2;   // DICT*DIN f32 (Wenc^T)
constexpr size_t WS_WETB   = WS_WETF + (size_t)DICT*DIN;     // DICT*DIN bf16 (Wenc^T)
constexpr size_t WS_WDB    = WS_WETB + (size_t)DICT*DIN/2;   // DICT*DIN bf16 (Wdec)
// ACC: 0 l2_sum, 1 l1_sum, 2 l0_sum, 3 aux_sq, 4 numdead, 5 anydead(int)

__device__ __forceinline__ unsigned umap(float f){
    unsigned u = __float_as_uint(f);
    return (u & 0x80000000u) ? ~u : (u | 0x80000000u);
}
__device__ __forceinline__ float posval(unsigned u){ return __uint_as_float(u & 0x7fffffffu); }
__device__ __forceinline__ unsigned short f2b(float f){   // RNE fp32 -> bf16
    unsigned u = __float_as_uint(f);
    return (unsigned short)((u + 0x7fffu + ((u >> 16) & 1u)) >> 16);
}
__device__ __forceinline__ float b2f(unsigned short h){ return __uint_as_float(((unsigned)h) << 16); }

__device__ __forceinline__ void gld_lds16(const void* g, void* l){
    __builtin_amdgcn_global_load_lds(
        (const __attribute__((address_space(1))) unsigned int*)g,
        (__attribute__((address_space(3))) unsigned int*)l, 16, 0, 0);
}

__device__ __forceinline__ int blk_count512(int c, int* s16, int par){
    #pragma unroll
    for (int off=32; off; off>>=1) c += __shfl_down(c, off);
    if ((threadIdx.x & 63) == 0) s16[par*8 + (threadIdx.x >> 6)] = c;
    __syncthreads();
    int tot = 0;
    #pragma unroll
    for (int w=0; w<8; w++) tot += s16[par*8+w];
    return tot;
}
__device__ __forceinline__ float blk_sum512(float v, float* s16, int par){
    #pragma unroll
    for (int off=32; off; off>>=1) v += __shfl_down(v, off);
    if ((threadIdx.x & 63) == 0) s16[par*8 + (threadIdx.x >> 6)] = v;
    __syncthreads();
    float t = 0.f;
    #pragma unroll
    for (int w=0; w<8; w++) t += s16[par*8+w];
    return t;
}
__device__ __forceinline__ float blk_sum256(float v, float* s8, int par){
    #pragma unroll
    for (int off=32; off; off>>=1) v += __shfl_down(v, off);
    if ((threadIdx.x & 63) == 0) s8[par*4 + (threadIdx.x >> 6)] = v;
    __syncthreads();
    float t = 0.f;
    #pragma unroll
    for (int w=0; w<4; w++) t += s8[par*4+w];
    return t;
}

// ---------------- kernel A: per-row unit-norm + bf16 copy of xe --------------
__global__ __launch_bounds__(256) void normalize_k(const float* __restrict__ x,
        const float* __restrict__ y, const float* __restrict__ bdec,
        float* __restrict__ ws){
    __shared__ float s8[8];
    int b = blockIdx.x; bool isy = b >= BATCH; int row = isy ? b - BATCH : b;
    const float* src = (isy ? y : x) + (size_t)row*DIN;
    int tid = threadIdx.x;
    float v0 = src[tid], v1 = src[tid+256], v2 = src[tid+512];
    float s = blk_sum256(v0+v1+v2, s8, 0);
    float mean = s * (1.f/(float)DIN);
    float d0 = v0-mean, d1 = v1-mean, d2 = v2-mean;
    float vs = blk_sum256(d0*d0+d1*d1+d2*d2, s8, 1);
    float sd = sqrtf(vs / (float)(DIN-1));
    float inv = 1.f / (sd + 1e-5f);
    if (isy){
        float* yn = ws + WS_YN + (size_t)row*DIN;
        yn[tid] = d0*inv; yn[tid+256] = d1*inv; yn[tid+512] = d2*inv;
        if (tid==0){ ws[WS_YMEAN+row] = mean; ws[WS_YSTD+row] = sd; }
    } else {
        float* xe = ws + WS_XENC + (size_t)row*DIN;
        unsigned short* xeb = (unsigned short*)(ws + WS_XEB) + (size_t)row*DIN;
        float e0 = d0*inv - bdec[tid];
        float e1 = d1*inv - bdec[tid+256];
        float e2 = d2*inv - bdec[tid+512];
        xe[tid] = e0; xe[tid+256] = e1; xe[tid+512] = e2;
        xeb[tid] = f2b(e0); xeb[tid+256] = f2b(e1); xeb[tid+512] = f2b(e2);
    }
}

// ---------------- kernel P1: Wenc transpose -> WeT f32 + WeT bf16 ------------
__global__ __launch_bounds__(256) void transpose_k(const float* __restrict__ W,
        float* __restrict__ Tf, unsigned short* __restrict__ Tb){
    __shared__ float t[32][33];
    int n0 = blockIdx.x*32, k0 = blockIdx.y*32;
    int r = threadIdx.x >> 5, c = threadIdx.x & 31;
    #pragma unroll
    for (int rr=r; rr<32; rr+=8) t[rr][c] = W[(size_t)(k0+rr)*DICT + n0 + c];
    __syncthreads();
    #pragma unroll
    for (int rr=r; rr<32; rr+=8){
        float v = t[c][rr];                 // = W[k0+c][n0+rr]
        Tf[(size_t)(n0+rr)*DIN + k0 + c] = v;
        Tb[(size_t)(n0+rr)*DIN + k0 + c] = f2b(v);
    }
}

// ---------------- kernel P2: Wdec -> bf16 ------------------------------------
__global__ __launch_bounds__(256) void wdecb_k(const float* __restrict__ W,
        unsigned short* __restrict__ Wb){
    size_t n4 = (size_t)DICT*DIN/4;
    for (size_t i = (size_t)blockIdx.x*256 + threadIdx.x; i < n4; i += (size_t)gridDim.x*256){
        float4 v = ((const float4*)W)[i];
        ushort4 o; o.x=f2b(v.x); o.y=f2b(v.y); o.z=f2b(v.z); o.w=f2b(v.w);
        ((ushort4*)Wb)[i] = o;
    }
}

// ---------------- kernel B: bf16 MFMA GEMM + relu ----------------------------
// C[m][n] = relu(sum_k A[m][k] B^T[n][k]).  128x128 tile, 4 waves, 16x16x32.
// LDS tiles [row][k] with 16B-chunk XOR swizzle (chunk ^= row&7) so the
// ds_read_b128 fragment reads are 2-way-only; staged via global_load_lds w=16
// with per-lane source-chunk permutation (dest is wave-uniform base + lane*16).
__global__ __launch_bounds__(256) void gemm_mfma(const unsigned short* __restrict__ Abf,
        const unsigned short* __restrict__ Bbf, float* __restrict__ C){
    __shared__ __align__(16) unsigned short As[128*64];
    __shared__ __align__(16) unsigned short Bs[128*64];
    const int tid = threadIdx.x;
    const int w = tid >> 6, lane = tid & 63;
    const int m0 = blockIdx.y*128, n0 = blockIdx.x*128;
    const int srow = lane >> 3;                  // 0..7 row within staging group
    const int schunk = (lane & 7) ^ srow;        // source chunk (xor swizzle)
    const int wm = (w >> 1)*64, wn = (w & 1)*64;
    f32x4 acc[16];
    #pragma unroll
    for (int i=0;i<16;i++) acc[i] = (f32x4){0.f,0.f,0.f,0.f};
    for (int kt = 0; kt < DIN; kt += 64){
        #pragma unroll
        for (int q=0;q<4;q++){
            int s = w*4 + q;                     // staging instr id 0..15
            int row = 8*s + srow;                // tile row 0..127
            gld_lds16(Abf + (size_t)(m0+row)*DIN + kt + schunk*8, &As[8*s*64]);
            gld_lds16(Bbf + (size_t)(n0+row)*DIN + kt + schunk*8, &Bs[8*s*64]);
        }
        __syncthreads();
        #pragma unroll
        for (int kk=0; kk<64; kk+=32){
            bf16x8 af[4], bfr[4];
            int ch = (kk>>3) + (lane>>4);
            #pragma unroll
            for (int i=0;i<4;i++){
                int row = wm + i*16 + (lane&15);
                af[i] = *(const bf16x8*)&As[row*64 + ((ch ^ (row&7))<<3)];
            }
            #pragma unroll
            for (int j=0;j<4;j++){
                int row = wn + j*16 + (lane&15);
                bfr[j] = *(const bf16x8*)&Bs[row*64 + ((ch ^ (row&7))<<3)];
            }
            #pragma unroll
            for (int i=0;i<4;i++)
                #pragma unroll
                for (int j=0;j<4;j++)
                    acc[i*4+j] = __builtin_amdgcn_mfma_f32_16x16x32_bf16(af[i], bfr[j], acc[i*4+j], 0,0,0);
        }
        __syncthreads();
    }
    // C/D layout: col = lane&15, row = (lane>>4)*4 + reg
    #pragma unroll
    for (int i=0;i<4;i++){
        #pragma unroll
        for (int r=0;r<4;r++){
            int m = m0 + wm + i*16 + (lane>>4)*4 + r;
            float* crow = C + (size_t)m*DICT + n0 + wn + (lane&15);
            #pragma unroll
            for (int j=0;j<4;j++)
                crow[j*16] = fmaxf(acc[i*4+j][r], 0.f);
        }
    }
}

// ---------------- kernel C1: approx cutoff -> exact refine -> top-32 ---------
__global__ __launch_bounds__(512) void topk_main(const float* __restrict__ acts,
        const float* __restrict__ WeTf, const float* __restrict__ Wdec,
        const float* __restrict__ bdec, float* __restrict__ ws,
        float* __restrict__ ypred_out){
    const int row = blockIdx.x, tid = threadIdx.x;
    const int lane = tid & 63, wid = tid >> 6;
    __shared__ int   s_i16[16];
    __shared__ float s_f16[16];
    __shared__ float s_x[DIN];
    __shared__ int   s_ci[CAND_MAX];
    __shared__ float s_cv[CAND_MAX];
    __shared__ int   s_li[KM];
    __shared__ float s_lv[KM];
    __shared__ int   s_n, s_m;
    const float* arow = acts + (size_t)row * DICT;
    const float* xrow = ws + WS_XENC + (size_t)row * DIN;
    unsigned u[NPT];
    #pragma unroll
    for (int i=0;i<NPT;i++) u[i] = umap(arow[tid + 512*i]);
    // stage xe row for refinement; init counters (radix barriers cover visibility)
    s_x[tid] = xrow[tid];
    if (tid < DIN-512) s_x[tid+512] = xrow[tid+512];
    if (tid == 0){ s_n = 0; s_m = 0; }

    // 32-bit radix: prefix = umap of approx 32nd-largest
    int par = 0;
    unsigned prefix = 0;
    for (int bit=31; bit>=0; bit--){
        unsigned cand = prefix | (1u<<bit);
        int c = 0;
        #pragma unroll
        for (int i=0;i<NPT;i++) c += (u[i] >= cand) ? 1 : 0;
        int tot = blk_count512(c, s_i16, par); par ^= 1;
        if (tot >= KM) prefix = cand;
    }
    float tc = posval(prefix) - CAND_DELTA;   // candidate threshold (acts >= 0)
    #pragma unroll
    for (int i=0;i<NPT;i++){
        if (posval(u[i]) > tc && u[i] >= UZERO){
            int p = atomicAdd(&s_n, 1);
            if (p < CAND_MAX) s_ci[p] = tid + 512*i;
        }
    }
    __syncthreads();
    int nc = s_n; if (nc > CAND_MAX) nc = CAND_MAX;
    // exact fp32 recompute of candidates (wave per candidate, strided)
    for (int c = wid; c < nc; c += 8){
        const float* wr = WeTf + (size_t)s_ci[c]*DIN;
        float p = 0.f;
        #pragma unroll
        for (int t=0; t<12; t++) p = fmaf(s_x[lane + 64*t], wr[lane + 64*t], p);
        #pragma unroll
        for (int off=32; off; off>>=1) p += __shfl_down(p, off);
        if (lane == 0) s_cv[c] = fmaxf(p, 0.f);
    }
    __syncthreads();
    // exact top-32 among candidates, stable (value desc, index asc)
    if (tid < nc){
        float vi = s_cv[tid]; int ii = s_ci[tid];
        int rank = 0;
        for (int j=0; j<nc; j++){
            float vj = s_cv[j];
            rank += (vj > vi) || (vj == vi && s_ci[j] < ii);
        }
        if (rank < KM){
            int p = atomicAdd(&s_m, 1);
            s_li[p] = ii; s_lv[p] = vi;
        }
    }
    __syncthreads();
    if (tid < KM){
        ((int*)ws)[WS_COLACT + s_li[tid]] = 1;
        ((int*)ws)[WS_SEL  + (size_t)row*KM + tid] = s_li[tid];
        ws[WS_SELV + (size_t)row*KM + tid] = s_lv[tid];
    }
    if (tid == 0){
        ((int*)ws)[WS_NSEL + row] = KM;
        float l1 = 0.f; int l0 = 0;
        for (int l=0;l<KM;l++){ l1 += s_lv[l]; l0 += (s_lv[l] > 0.f); }
        atomicAdd(&ws[WS_ACC+1], l1);
        atomicAdd(&ws[WS_ACC+2], (float)l0);
    }
    __syncthreads();
    float ym = ws[WS_YMEAN+row], ys = ws[WS_YSTD+row];
    float l2loc = 0.f;
    for (int c = tid; c < DIN; c += 512){
        float acc = bdec[c];
        #pragma unroll 4
        for (int l=0;l<KM;l++) acc = fmaf(s_lv[l], Wdec[(size_t)s_li[l]*DIN + c], acc);
        float ynv = ws[WS_YN + (size_t)row*DIN + c];
        float d = acc - ynv;
        l2loc += d*d;
        ws[WS_RES + (size_t)row*DIN + c] = ynv - acc;
        ypred_out[(size_t)row*DIN + c] = fmaf(acc, ys, ym);
    }
    float l2t = blk_sum512(l2loc, s_f16, 0);
    if (tid==0) atomicAdd(&ws[WS_ACC+0], l2t);
}

// ---------------- kernel D: dead-feature bookkeeping -------------------------
__global__ __launch_bounds__(256) void dead_update(const float* __restrict__ nb,
        float* __restrict__ ws){
    int j = blockIdx.x*256 + threadIdx.x;
    int lane = threadIdx.x & 63;
    int act = ((const int*)ws)[WS_COLACT + j];
    float nbn = act ? 0.f : nb[j] + 1.f;
    bool dead = nbn >= 100.0f;
    unsigned long long bal = __ballot(dead ? 1 : 0);
    if (lane == 0){
        unsigned* db = (unsigned*)(ws + WS_DB);
        int w = j >> 5;
        db[w]   = (unsigned)bal;
        db[w+1] = (unsigned)(bal >> 32);
        if (bal) atomicOr(((int*)ws) + WS_ACC + 5, 1);
    }
    int c = (nbn > 100.0f) ? 1 : 0;
    #pragma unroll
    for (int off=32; off; off>>=1) c += __shfl_down(c, off);
    if (lane == 0 && c) atomicAdd(&ws[WS_ACC+4], (float)c);
}

// ---------------- kernel E: aux top-512, sparse rewrite, aux loss ------------
__global__ __launch_bounds__(512) void aux_and_write(float* __restrict__ acts,
        const unsigned short* __restrict__ WdB, float* __restrict__ ws){
    const int row = blockIdx.x, tid = threadIdx.x;
    const int lane = tid & 63, wid = tid >> 6;
    __shared__ int      s_i16[16];
    __shared__ float    s_f16[16];
    __shared__ unsigned s_db[DICT/32];
    __shared__ int      s_li[KA];
    __shared__ float    s_lv[KA];
    __shared__ int      s_n;
    __shared__ float    s_red[DIN];
    float* arow = acts + (size_t)row * DICT;

    for (int i=tid; i<DICT/32; i+=512) s_db[i] = ((const unsigned*)(ws + WS_DB))[i];
    if (tid==0) s_n = 0;
    __syncthreads();

    unsigned u[NPT];
    unsigned long long dm = 0ull;
    #pragma unroll
    for (int i=0;i<NPT;i++){
        int j = tid + 512*i;
        u[i] = umap(arow[j]);
        if ((s_db[j>>5] >> (j&31)) & 1u) dm |= (1ull << i);
    }

    int par = 0;
    unsigned prefix = 0;
    for (int bit=31; bit>=0; bit--){
        unsigned cand = prefix | (1u<<bit);
        int c = 0;
        #pragma unroll
        for (int i=0;i<NPT;i++){
            unsigned um = ((dm>>i)&1ull) ? u[i] : UMNEG1;
            c += (um >= cand) ? 1 : 0;
        }
        int tot = blk_count512(c, s_i16, par); par ^= 1;
        if (tot >= KA) prefix = cand;
    }
    int cgt=0, ceq=0;
    #pragma unroll
    for (int i=0;i<NPT;i++){
        unsigned um = ((dm>>i)&1ull) ? u[i] : UMNEG1;
        cgt += (um > prefix); ceq += (um == prefix);
    }
    int cgt_t = blk_count512(cgt, s_i16, par); par ^= 1;
    int ceq_t = blk_count512(ceq, s_i16, par); par ^= 1;
    int m = KA - cgt_t;
    // collect strictly-positive selected (zeros/-1 contribute nothing to y_aux)
    #pragma unroll
    for (int i=0;i<NPT;i++){
        unsigned um = ((dm>>i)&1ull) ? u[i] : UMNEG1;
        if (um > UZERO && um > prefix){
            int p = atomicAdd(&s_n, 1);
            s_li[p] = tid + 512*i; s_lv[p] = posval(u[i]);
        }
    }
    __syncthreads();
    if (prefix > UZERO && m > 0){
        if (ceq_t == m){
            #pragma unroll
            for (int i=0;i<NPT;i++){
                unsigned um = ((dm>>i)&1ull) ? u[i] : UMNEG1;
                if (um == prefix){
                    int p = atomicAdd(&s_n, 1);
                    s_li[p] = tid + 512*i; s_lv[p] = posval(prefix);
                }
            }
        } else {
            int seen = 0;
            for (int i=0;i<NPT;i++){
                int j = tid + 512*i;
                unsigned uv = umap(arow[j]);
                unsigned um = ((s_db[j>>5]>>(j&31))&1u) ? uv : UMNEG1;
                bool match = (um == prefix);
                unsigned long long bal = __ballot(match ? 1 : 0);
                if (lane==0) s_i16[par*8+wid] = __popcll(bal);
                __syncthreads();
                int before=0, tot=0;
                for (int w=0;w<8;w++){ int v=s_i16[par*8+w]; if (w<wid) before+=v; tot+=v; }
                par ^= 1;
                int rank = seen + before + __popcll(bal & ((1ull<<lane)-1ull));
                if (match && rank < m){
                    int p = atomicAdd(&s_n, 1);
                    s_li[p] = j; s_lv[p] = posval(uv);
                }
                seen += tot;
            }
        }
    }
    __syncthreads();
    int n = s_n;

    // rewrite acts row -> exact sparse output: zero all, scatter exact top-32
    float4 z4 = make_float4(0.f,0.f,0.f,0.f);
    #pragma unroll
    for (int i=0;i<NPT/4;i++) ((float4*)arow)[tid + 512*i] = z4;
    __syncthreads();
    if (tid < KM){
        int j = ((const int*)ws)[WS_SEL + (size_t)row*KM + tid];
        arow[j] = ws[WS_SELV + (size_t)row*KM + tid];
    }

    // aux epilogue: y_aux = sum vals * W_dec(bf16) rows; aux_sq += ||y_aux - res||^2
    float4 a = make_float4(0.f,0.f,0.f,0.f);
    int g = tid / 192;
    int cq = (tid % 192) * 4;
    if (g < 2){
        for (int l=g; l<n; l+=2){
            float v = s_lv[l];
            const ushort4 wq = *(const ushort4*)&WdB[(size_t)s_li[l]*DIN + cq];
            a.x = fmaf(v, b2f(wq.x), a.x); a.y = fmaf(v, b2f(wq.y), a.y);
            a.z = fmaf(v, b2f(wq.z), a.z); a.w = fmaf(v, b2f(wq.w), a.w);
        }
    }
    __syncthreads();
    if (g == 1) *(float4*)&s_red[cq] = a;
    __syncthreads();
    float ss = 0.f;
    if (g == 0){
        float4 b = *(const float4*)&s_red[cq];
        const float4 r = *(const float4*)&ws[WS_RES + (size_t)row*DIN + cq];
        float dx = a.x + b.x - r.x, dy = a.y + b.y - r.y;
        float dz = a.z + b.z - r.z, dw = a.w + b.w - r.w;
        ss = dx*dx + dy*dy + dz*dz + dw*dw;
    }
    float tot = blk_sum512(ss, s_f16, 0);
    if (tid==0) atomicAdd(&ws[WS_ACC+3], tot);
}

// ---------------- kernel F: scalars ------------------------------------------
__global__ void finalize_k(const float* __restrict__ ws, float* __restrict__ out){
    if (threadIdx.x == 0){
        float l2   = ws[WS_ACC+0] / (float)((size_t)BATCH*DIN);
        float l1n  = ws[WS_ACC+1] / (float)BATCH;
        float l1l  = L1_COEFF * l1n;
        float l0   = ws[WS_ACC+2] / (float)BATCH;
        float auxm = AUX_PENALTY * (ws[WS_ACC+3] / (float)((size_t)BATCH*DIN));
        int any    = ((const int*)ws)[WS_ACC+5];
        float auxl = any ? auxm : 0.f;
        out[0] = l2 + l1l + auxl;
        out[1] = l2;
        out[2] = l1l;
        out[3] = l0;
        out[4] = l1n;
        out[5] = auxl;
        out[6] = ws[WS_ACC+4];
    }
}

extern "C" void kernel_launch(void* const* d_in, const int* in_sizes, int n_in,
                              void* d_out, int out_size, void* d_ws, size_t ws_size,
                              hipStream_t stream){
    const float* x_in = (const float*)d_in[0];
    const float* y_t  = (const float*)d_in[1];
    const float* nb   = (const float*)d_in[2];
    const float* Wenc = (const float*)d_in[3];
    const float* Wdec = (const float*)d_in[4];
    const float* bdec = (const float*)d_in[5];
    float* out  = (float*)d_out;
    float* ws   = (float*)d_ws;
    float* acts = out + (size_t)BATCH*DIN;                       // acts_sparse region
    float* scal = out + (size_t)BATCH*DIN + (size_t)BATCH*DICT;  // 7 scalars

    unsigned short* xeb  = (unsigned short*)(ws + WS_XEB);
    float*          wetf = ws + WS_WETF;
    unsigned short* wetb = (unsigned short*)(ws + WS_WETB);
    unsigned short* wdb  = (unsigned short*)(ws + WS_WDB);

    hipMemsetAsync(ws + WS_COLACT, 0, (DICT + 8) * sizeof(float), stream);
    normalize_k<<<2*BATCH, 256, 0, stream>>>(x_in, y_t, bdec, ws);
    transpose_k<<<dim3(DICT/32, DIN/32), 256, 0, stream>>>(Wenc, wetf, wetb);
    wdecb_k<<<2048, 256, 0, stream>>>(Wdec, wdb);
    gemm_mfma<<<dim3(DICT/128, BATCH/128), 256, 0, stream>>>(xeb, wetb, acts);
    topk_main<<<BATCH, 512, 0, stream>>>(acts, wetf, Wdec, bdec, ws, out);
    dead_update<<<DICT/256, 256, 0, stream>>>(nb, ws);
    aux_and_write<<<BATCH, 512, 0, stream>>>(acts, wdb, ws);
    finalize_k<<<1, 64, 0, stream>>>(ws, scal);
}

// Round 4
// 859.957 us; speedup vs baseline: 2.3252x; 1.6104x over previous
//
#include <hip/hip_runtime.h>
#include <math.h>

#define BATCH 2048
#define DIN 768
#define DICT 24576
#define KM 32
#define KA 512
#define NPT 48            // DICT / 512 elements per thread
#define L1_COEFF 0.001f
#define AUX_PENALTY 0.03125f
#define CAND_MAX 128
#define CAND_DELTA 0.08f
#define AUXC (KA + 64)    // aux list capacity (quota + bf16 ties)

typedef __attribute__((ext_vector_type(8))) short bf16x8;
typedef __attribute__((ext_vector_type(8))) unsigned short u16x8;
typedef __attribute__((ext_vector_type(4))) float f32x4;

// ---------------- ws layout (float slots) ----------------
constexpr size_t WS_XENC   = 0;                              // BATCH*DIN f32 (refinement)
constexpr size_t WS_YN     = WS_XENC + (size_t)BATCH*DIN;    // BATCH*DIN
constexpr size_t WS_YMEAN  = WS_YN + (size_t)BATCH*DIN;      // BATCH
constexpr size_t WS_YSTD   = WS_YMEAN + BATCH;               // BATCH
constexpr size_t WS_RES    = WS_YSTD + BATCH;                // BATCH*DIN
constexpr size_t WS_NSEL   = WS_RES + (size_t)BATCH*DIN;     // BATCH (int)
constexpr size_t WS_SEL    = WS_NSEL + BATCH;                // BATCH*KM (int)
constexpr size_t WS_SELV   = WS_SEL + (size_t)BATCH*KM;      // BATCH*KM (float, exact vals)
constexpr size_t WS_COLACT = WS_SELV + (size_t)BATCH*KM;     // DICT (int, memset 0)
constexpr size_t WS_ACC    = WS_COLACT + DICT;               // 8 (memset 0)
constexpr size_t WS_DB     = WS_ACC + 8;                     // DICT/32 words
constexpr size_t WS_XEB    = WS_DB + DICT/32;                // BATCH*DIN bf16 -> /2 slots
constexpr size_t WS_WETF   = WS_XEB + (size_t)BATCH*DIN/2;   // DICT*DIN f32 (Wenc^T)
constexpr size_t WS_WETB   = WS_WETF + (size_t)DICT*DIN;     // DICT*DIN bf16 (Wenc^T)
constexpr size_t WS_WDB    = WS_WETB + (size_t)DICT*DIN/2;   // DICT*DIN bf16 (Wdec)
// ACC: 0 l2_sum, 1 l1_sum, 2 l0_sum, 3 aux_sq, 4 numdead, 5 anydead(int)

__device__ __forceinline__ unsigned short f2b(float f){   // RNE fp32 -> bf16
    unsigned u = __float_as_uint(f);
    return (unsigned short)((u + 0x7fffu + ((u >> 16) & 1u)) >> 16);
}
__device__ __forceinline__ float b2f(unsigned short h){ return __uint_as_float(((unsigned)h) << 16); }

__device__ __forceinline__ void gld_lds16(const void* g, void* l){
    __builtin_amdgcn_global_load_lds(
        (const __attribute__((address_space(1))) unsigned int*)g,
        (__attribute__((address_space(3))) unsigned int*)l, 16, 0, 0);
}

__device__ __forceinline__ int blk_count512(int c, int* s16, int par){
    #pragma unroll
    for (int off=32; off; off>>=1) c += __shfl_down(c, off);
    if ((threadIdx.x & 63) == 0) s16[par*8 + (threadIdx.x >> 6)] = c;
    __syncthreads();
    int tot = 0;
    #pragma unroll
    for (int w=0; w<8; w++) tot += s16[par*8+w];
    return tot;
}
__device__ __forceinline__ float blk_sum512(float v, float* s16, int par){
    #pragma unroll
    for (int off=32; off; off>>=1) v += __shfl_down(v, off);
    if ((threadIdx.x & 63) == 0) s16[par*8 + (threadIdx.x >> 6)] = v;
    __syncthreads();
    float t = 0.f;
    #pragma unroll
    for (int w=0; w<8; w++) t += s16[par*8+w];
    return t;
}
__device__ __forceinline__ float blk_sum256(float v, float* s8, int par){
    #pragma unroll
    for (int off=32; off; off>>=1) v += __shfl_down(v, off);
    if ((threadIdx.x & 63) == 0) s8[par*4 + (threadIdx.x >> 6)] = v;
    __syncthreads();
    float t = 0.f;
    #pragma unroll
    for (int w=0; w<4; w++) t += s8[par*4+w];
    return t;
}

// ---------------- kernel A: per-row unit-norm + bf16 copy of xe --------------
__global__ __launch_bounds__(256) void normalize_k(const float* __restrict__ x,
        const float* __restrict__ y, const float* __restrict__ bdec,
        float* __restrict__ ws){
    __shared__ float s8[8];
    int b = blockIdx.x; bool isy = b >= BATCH; int row = isy ? b - BATCH : b;
    const float* src = (isy ? y : x) + (size_t)row*DIN;
    int tid = threadIdx.x;
    float v0 = src[tid], v1 = src[tid+256], v2 = src[tid+512];
    float s = blk_sum256(v0+v1+v2, s8, 0);
    float mean = s * (1.f/(float)DIN);
    float d0 = v0-mean, d1 = v1-mean, d2 = v2-mean;
    float vs = blk_sum256(d0*d0+d1*d1+d2*d2, s8, 1);
    float sd = sqrtf(vs / (float)(DIN-1));
    float inv = 1.f / (sd + 1e-5f);
    if (isy){
        float* yn = ws + WS_YN + (size_t)row*DIN;
        yn[tid] = d0*inv; yn[tid+256] = d1*inv; yn[tid+512] = d2*inv;
        if (tid==0){ ws[WS_YMEAN+row] = mean; ws[WS_YSTD+row] = sd; }
    } else {
        float* xe = ws + WS_XENC + (size_t)row*DIN;
        unsigned short* xeb = (unsigned short*)(ws + WS_XEB) + (size_t)row*DIN;
        float e0 = d0*inv - bdec[tid];
        float e1 = d1*inv - bdec[tid+256];
        float e2 = d2*inv - bdec[tid+512];
        xe[tid] = e0; xe[tid+256] = e1; xe[tid+512] = e2;
        xeb[tid] = f2b(e0); xeb[tid+256] = f2b(e1); xeb[tid+512] = f2b(e2);
    }
}

// ---------------- kernel P1: Wenc transpose -> WeT f32 + WeT bf16 ------------
__global__ __launch_bounds__(256) void transpose_k(const float* __restrict__ W,
        float* __restrict__ Tf, unsigned short* __restrict__ Tb){
    __shared__ float t[32][33];
    int n0 = blockIdx.x*32, k0 = blockIdx.y*32;
    int r = threadIdx.x >> 5, c = threadIdx.x & 31;
    #pragma unroll
    for (int rr=r; rr<32; rr+=8) t[rr][c] = W[(size_t)(k0+rr)*DICT + n0 + c];
    __syncthreads();
    #pragma unroll
    for (int rr=r; rr<32; rr+=8){
        float v = t[c][rr];                 // = W[k0+c][n0+rr]
        Tf[(size_t)(n0+rr)*DIN + k0 + c] = v;
        Tb[(size_t)(n0+rr)*DIN + k0 + c] = f2b(v);
    }
}

// ---------------- kernel P2: Wdec -> bf16 ------------------------------------
__global__ __launch_bounds__(256) void wdecb_k(const float* __restrict__ W,
        unsigned short* __restrict__ Wb){
    size_t n4 = (size_t)DICT*DIN/4;
    for (size_t i = (size_t)blockIdx.x*256 + threadIdx.x; i < n4; i += (size_t)gridDim.x*256){
        float4 v = ((const float4*)W)[i];
        ushort4 o; o.x=f2b(v.x); o.y=f2b(v.y); o.z=f2b(v.z); o.w=f2b(v.w);
        ((ushort4*)Wb)[i] = o;
    }
}

// ---------------- kernel B: bf16 MFMA GEMM + relu -> bf16 acts ---------------
__global__ __launch_bounds__(256) void gemm_mfma(const unsigned short* __restrict__ Abf,
        const unsigned short* __restrict__ Bbf, unsigned short* __restrict__ C){
    __shared__ __align__(16) unsigned short As[128*64];
    __shared__ __align__(16) unsigned short Bs[128*64];
    const int tid = threadIdx.x;
    const int w = tid >> 6, lane = tid & 63;
    const int m0 = blockIdx.y*128, n0 = blockIdx.x*128;
    const int srow = lane >> 3;                  // 0..7 row within staging group
    const int schunk = (lane & 7) ^ srow;        // source chunk (xor swizzle)
    const int wm = (w >> 1)*64, wn = (w & 1)*64;
    f32x4 acc[16];
    #pragma unroll
    for (int i=0;i<16;i++) acc[i] = (f32x4){0.f,0.f,0.f,0.f};
    for (int kt = 0; kt < DIN; kt += 64){
        #pragma unroll
        for (int q=0;q<4;q++){
            int s = w*4 + q;                     // staging instr id 0..15
            int row = 8*s + srow;                // tile row 0..127
            gld_lds16(Abf + (size_t)(m0+row)*DIN + kt + schunk*8, &As[8*s*64]);
            gld_lds16(Bbf + (size_t)(n0+row)*DIN + kt + schunk*8, &Bs[8*s*64]);
        }
        __syncthreads();
        #pragma unroll
        for (int kk=0; kk<64; kk+=32){
            bf16x8 af[4], bfr[4];
            int ch = (kk>>3) + (lane>>4);
            #pragma unroll
            for (int i=0;i<4;i++){
                int row = wm + i*16 + (lane&15);
                af[i] = *(const bf16x8*)&As[row*64 + ((ch ^ (row&7))<<3)];
            }
            #pragma unroll
            for (int j=0;j<4;j++){
                int row = wn + j*16 + (lane&15);
                bfr[j] = *(const bf16x8*)&Bs[row*64 + ((ch ^ (row&7))<<3)];
            }
            #pragma unroll
            for (int i=0;i<4;i++)
                #pragma unroll
                for (int j=0;j<4;j++)
                    acc[i*4+j] = __builtin_amdgcn_mfma_f32_16x16x32_bf16(af[i], bfr[j], acc[i*4+j], 0,0,0);
        }
        __syncthreads();
    }
    // C/D layout: col = lane&15, row = (lane>>4)*4 + reg.  +0.0f kills -0.
    #pragma unroll
    for (int i=0;i<4;i++){
        #pragma unroll
        for (int r=0;r<4;r++){
            int m = m0 + wm + i*16 + (lane>>4)*4 + r;
            unsigned short* crow = C + (size_t)m*DICT + n0 + wn + (lane&15);
            #pragma unroll
            for (int j=0;j<4;j++)
                crow[j*16] = f2b(fmaxf(acc[i*4+j][r], 0.f) + 0.0f);
        }
    }
}

// ---------------- kernel C1: bf16 radix cutoff -> exact refine -> top-32 -----
__global__ __launch_bounds__(512) void topk_main(const unsigned short* __restrict__ actsb,
        const float* __restrict__ WeTf, const float* __restrict__ Wdec,
        const float* __restrict__ bdec, float* __restrict__ ws,
        float* __restrict__ ypred_out){
    const int row = blockIdx.x, tid = threadIdx.x;
    const int lane = tid & 63, wid = tid >> 6;
    __shared__ int   s_i16[16];
    __shared__ float s_f16[16];
    __shared__ float s_x[DIN];
    __shared__ int   s_ci[CAND_MAX];
    __shared__ float s_cv[CAND_MAX];
    __shared__ int   s_li[KM];
    __shared__ float s_lv[KM];
    __shared__ int   s_n, s_m;
    const unsigned short* arow = actsb + (size_t)row * DICT;
    const float* xrow = ws + WS_XENC + (size_t)row * DIN;
    unsigned short h[NPT];
    #pragma unroll
    for (int i=0;i<6;i++){
        u16x8 v = *(const u16x8*)&arow[i*4096 + tid*8];
        #pragma unroll
        for (int e=0;e<8;e++) h[i*8+e] = v[e];
    }
    s_x[tid] = xrow[tid];
    if (tid < DIN-512) s_x[tid+512] = xrow[tid+512];
    if (tid == 0){ s_n = 0; s_m = 0; }

    // 15-bit radix on bf16 pattern: prefix = 32nd-largest stored value
    int par = 0;
    unsigned prefix = 0;
    for (int bit=14; bit>=0; bit--){
        unsigned cand = prefix | (1u<<bit);
        int c = 0;
        #pragma unroll
        for (int q=0;q<NPT;q++) c += ((unsigned)h[q] >= cand) ? 1 : 0;
        int tot = blk_count512(c, s_i16, par); par ^= 1;
        if (tot >= KM) prefix = cand;
    }
    float tc = b2f((unsigned short)prefix) - CAND_DELTA;  // candidate threshold
    #pragma unroll
    for (int q=0;q<NPT;q++){
        if (b2f(h[q]) > tc){
            int p = atomicAdd(&s_n, 1);
            if (p < CAND_MAX) s_ci[p] = (q>>3)*4096 + tid*8 + (q&7);
        }
    }
    __syncthreads();
    int nc = s_n; if (nc > CAND_MAX) nc = CAND_MAX;
    // exact fp32 recompute of candidates (wave per candidate, strided)
    for (int c = wid; c < nc; c += 8){
        const float* wr = WeTf + (size_t)s_ci[c]*DIN;
        float p = 0.f;
        #pragma unroll
        for (int t=0; t<12; t++) p = fmaf(s_x[lane + 64*t], wr[lane + 64*t], p);
        #pragma unroll
        for (int off=32; off; off>>=1) p += __shfl_down(p, off);
        if (lane == 0) s_cv[c] = fmaxf(p, 0.f);
    }
    __syncthreads();
    // exact top-32 among candidates, stable (value desc, index asc)
    if (tid < nc){
        float vi = s_cv[tid]; int ii = s_ci[tid];
        int rank = 0;
        for (int j=0; j<nc; j++){
            float vj = s_cv[j];
            rank += (vj > vi) || (vj == vi && s_ci[j] < ii);
        }
        if (rank < KM){
            int p = atomicAdd(&s_m, 1);
            s_li[p] = ii; s_lv[p] = vi;
        }
    }
    __syncthreads();
    if (tid < KM){
        ((int*)ws)[WS_COLACT + s_li[tid]] = 1;
        ((int*)ws)[WS_SEL  + (size_t)row*KM + tid] = s_li[tid];
        ws[WS_SELV + (size_t)row*KM + tid] = s_lv[tid];
    }
    if (tid == 0){
        float l1 = 0.f; int l0 = 0;
        for (int l=0;l<KM;l++){ l1 += s_lv[l]; l0 += (s_lv[l] > 0.f); }
        atomicAdd(&ws[WS_ACC+1], l1);
        atomicAdd(&ws[WS_ACC+2], (float)l0);
    }
    __syncthreads();
    float ym = ws[WS_YMEAN+row], ys = ws[WS_YSTD+row];
    float l2loc = 0.f;
    for (int c = tid; c < DIN; c += 512){
        float acc = bdec[c];
        #pragma unroll 4
        for (int l=0;l<KM;l++) acc = fmaf(s_lv[l], Wdec[(size_t)s_li[l]*DIN + c], acc);
        float ynv = ws[WS_YN + (size_t)row*DIN + c];
        float d = acc - ynv;
        l2loc += d*d;
        ws[WS_RES + (size_t)row*DIN + c] = ynv - acc;
        ypred_out[(size_t)row*DIN + c] = fmaf(acc, ys, ym);
    }
    float l2t = blk_sum512(l2loc, s_f16, 0);
    if (tid==0) atomicAdd(&ws[WS_ACC+0], l2t);
}

// ---------------- kernel D: dead-feature bookkeeping -------------------------
__global__ __launch_bounds__(256) void dead_update(const float* __restrict__ nb,
        float* __restrict__ ws){
    int j = blockIdx.x*256 + threadIdx.x;
    int lane = threadIdx.x & 63;
    int act = ((const int*)ws)[WS_COLACT + j];
    float nbn = act ? 0.f : nb[j] + 1.f;
    bool dead = nbn >= 100.0f;
    unsigned long long bal = __ballot(dead ? 1 : 0);
    if (lane == 0){
        unsigned* db = (unsigned*)(ws + WS_DB);
        int w = j >> 5;
        db[w]   = (unsigned)bal;
        db[w+1] = (unsigned)(bal >> 32);
        if (bal) atomicOr(((int*)ws) + WS_ACC + 5, 1);
    }
    int c = (nbn > 100.0f) ? 1 : 0;
    #pragma unroll
    for (int off=32; off; off>>=1) c += __shfl_down(c, off);
    if (lane == 0 && c) atomicAdd(&ws[WS_ACC+4], (float)c);
}

// ---------------- kernel E: aux select (bf16 grain, ties incl.) + aux loss ---
__global__ __launch_bounds__(512) void aux_k(const unsigned short* __restrict__ actsb,
        const unsigned short* __restrict__ WdB, float* __restrict__ ws){
    const int row = blockIdx.x, tid = threadIdx.x;
    const int lane = tid & 63, wid = tid >> 6;
    __shared__ int      s_i16[16];
    __shared__ float    s_f16[16];
    __shared__ unsigned s_db[DICT/32];
    __shared__ int      s_li[AUXC];
    __shared__ float    s_lv[AUXC];
    __shared__ int      s_n;
    __shared__ float    s_red[8*DIN];            // per-wave y_aux partials
    const unsigned short* arow = actsb + (size_t)row * DICT;

    for (int i=tid; i<DICT/32; i+=512) s_db[i] = ((const unsigned*)(ws + WS_DB))[i];
    if (tid==0) s_n = 0;
    __syncthreads();

    // keys: bf16 bits if (dead && positive) else 0
    unsigned short key[NPT];
    #pragma unroll
    for (int i=0;i<6;i++){
        u16x8 v = *(const u16x8*)&arow[i*4096 + tid*8];
        unsigned byte = (s_db[i*128 + (tid>>2)] >> ((tid&3)*8)) & 0xFFu;
        #pragma unroll
        for (int e=0;e<8;e++){
            unsigned short hv = v[e];
            key[i*8+e] = (((byte>>e)&1u) && hv) ? hv : 0;
        }
    }

    // 15-bit radix: prefix = 512th-largest key (0 if fewer than 512 positives)
    int par = 0;
    unsigned prefix = 0;
    for (int bit=14; bit>=0; bit--){
        unsigned cand = prefix | (1u<<bit);
        int c = 0;
        #pragma unroll
        for (int q=0;q<NPT;q++) c += ((unsigned)key[q] >= cand) ? 1 : 0;
        int tot = blk_count512(c, s_i16, par); par ^= 1;
        if (tot >= KA) prefix = cand;
    }
    unsigned thr = prefix ? prefix : 1u;   // include all ties; all positives if <512
    #pragma unroll
    for (int q=0;q<NPT;q++){
        if ((unsigned)key[q] >= thr){
            int p = atomicAdd(&s_n, 1);
            if (p < AUXC){
                s_li[p] = (q>>3)*4096 + tid*8 + (q&7);
                s_lv[p] = b2f(key[q]);
            }
        }
    }
    __syncthreads();
    int n = s_n; if (n > AUXC) n = AUXC;

    // 8-way wave-parallel gather: wave handles rows l = wid (mod 8);
    // lane covers 12 contiguous cols [12*lane, 12*lane+12)
    float a[12];
    #pragma unroll
    for (int i=0;i<12;i++) a[i] = 0.f;
    const int base = lane*12;
    for (int l = wid; l < n; l += 8){
        float v = s_lv[l];
        const unsigned short* wr = WdB + (size_t)s_li[l]*DIN + base;
        ushort4 q0 = *(const ushort4*)wr;
        ushort4 q1 = *(const ushort4*)(wr+4);
        ushort4 q2 = *(const ushort4*)(wr+8);
        a[0] = fmaf(v, b2f(q0.x), a[0]); a[1] = fmaf(v, b2f(q0.y), a[1]);
        a[2] = fmaf(v, b2f(q0.z), a[2]); a[3] = fmaf(v, b2f(q0.w), a[3]);
        a[4] = fmaf(v, b2f(q1.x), a[4]); a[5] = fmaf(v, b2f(q1.y), a[5]);
        a[6] = fmaf(v, b2f(q1.z), a[6]); a[7] = fmaf(v, b2f(q1.w), a[7]);
        a[8] = fmaf(v, b2f(q2.x), a[8]); a[9] = fmaf(v, b2f(q2.y), a[9]);
        a[10]= fmaf(v, b2f(q2.z), a[10]); a[11]= fmaf(v, b2f(q2.w), a[11]);
    }
    float* pr = &s_red[wid*DIN + base];
    *(float4*)pr     = make_float4(a[0],a[1],a[2],a[3]);
    *(float4*)(pr+4) = make_float4(a[4],a[5],a[6],a[7]);
    *(float4*)(pr+8) = make_float4(a[8],a[9],a[10],a[11]);
    __syncthreads();
    float ss = 0.f;
    for (int c = tid; c < DIN; c += 512){
        float s = 0.f;
        #pragma unroll
        for (int w=0; w<8; w++) s += s_red[w*DIN + c];
        float d = s - ws[WS_RES + (size_t)row*DIN + c];
        ss += d*d;
    }
    float tot = blk_sum512(ss, s_f16, 0);
    if (tid==0) atomicAdd(&ws[WS_ACC+3], tot);
}

// ---------------- kernel Z: zero + scatter the sparse fp32 output ------------
__global__ __launch_bounds__(256) void zscatter(const float* __restrict__ ws,
        float* __restrict__ acts){
    const int row = blockIdx.x, tid = threadIdx.x;
    float4 z = make_float4(0.f,0.f,0.f,0.f);
    float4* arow4 = (float4*)(acts + (size_t)row*DICT);
    #pragma unroll
    for (int i=0;i<24;i++) arow4[tid + 256*i] = z;
    __syncthreads();
    if (tid < KM){
        int j   = ((const int*)ws)[WS_SEL + (size_t)row*KM + tid];
        float v = ws[WS_SELV + (size_t)row*KM + tid];
        (acts + (size_t)row*DICT)[j] = v;
    }
}

// ---------------- kernel F: scalars ------------------------------------------
__global__ void finalize_k(const float* __restrict__ ws, float* __restrict__ out){
    if (threadIdx.x == 0){
        float l2   = ws[WS_ACC+0] / (float)((size_t)BATCH*DIN);
        float l1n  = ws[WS_ACC+1] / (float)BATCH;
        float l1l  = L1_COEFF * l1n;
        float l0   = ws[WS_ACC+2] / (float)BATCH;
        float auxm = AUX_PENALTY * (ws[WS_ACC+3] / (float)((size_t)BATCH*DIN));
        int any    = ((const int*)ws)[WS_ACC+5];
        float auxl = any ? auxm : 0.f;
        out[0] = l2 + l1l + auxl;
        out[1] = l2;
        out[2] = l1l;
        out[3] = l0;
        out[4] = l1n;
        out[5] = auxl;
        out[6] = ws[WS_ACC+4];
    }
}

extern "C" void kernel_launch(void* const* d_in, const int* in_sizes, int n_in,
                              void* d_out, int out_size, void* d_ws, size_t ws_size,
                              hipStream_t stream){
    const float* x_in = (const float*)d_in[0];
    const float* y_t  = (const float*)d_in[1];
    const float* nb   = (const float*)d_in[2];
    const float* Wenc = (const float*)d_in[3];
    const float* Wdec = (const float*)d_in[4];
    const float* bdec = (const float*)d_in[5];
    float* out  = (float*)d_out;
    float* ws   = (float*)d_ws;
    float* acts = out + (size_t)BATCH*DIN;                       // acts_sparse region
    float* scal = out + (size_t)BATCH*DIN + (size_t)BATCH*DICT;  // 7 scalars
    // bf16 acts lives in the first half of the acts output region (overwritten
    // by zscatter at the end of every launch)
    unsigned short* actsb = (unsigned short*)acts;

    unsigned short* xeb  = (unsigned short*)(ws + WS_XEB);
    float*          wetf = ws + WS_WETF;
    unsigned short* wetb = (unsigned short*)(ws + WS_WETB);
    unsigned short* wdb  = (unsigned short*)(ws + WS_WDB);

    hipMemsetAsync(ws + WS_COLACT, 0, (DICT + 8) * sizeof(float), stream);
    normalize_k<<<2*BATCH, 256, 0, stream>>>(x_in, y_t, bdec, ws);
    transpose_k<<<dim3(DICT/32, DIN/32), 256, 0, stream>>>(Wenc, wetf, wetb);
    wdecb_k<<<2048, 256, 0, stream>>>(Wdec, wdb);
    gemm_mfma<<<dim3(DICT/128, BATCH/128), 256, 0, stream>>>(xeb, wetb, actsb);
    topk_main<<<BATCH, 512, 0, stream>>>(actsb, wetf, Wdec, bdec, ws, out);
    dead_update<<<DICT/256, 256, 0, stream>>>(nb, ws);
    aux_k<<<BATCH, 512, 0, stream>>>(actsb, wdb, ws);
    zscatter<<<BATCH, 256, 0, stream>>>(ws, acts);
    finalize_k<<<1, 64, 0, stream>>>(ws, scal);
}